// Round 7
// baseline (576.430 us; speedup 1.0000x reference)
//
#include <hip/hip_runtime.h>
#include <hip/hip_bf16.h>

#define B_  4
#define D_  1024
#define L_  2048
#define H_  8
#define HD_ 128

typedef __attribute__((ext_vector_type(8))) short bf16x8;
typedef __attribute__((ext_vector_type(4))) float f32x4;

static __device__ __forceinline__ ushort f2bf(float f) {
    // round-to-nearest-even fp32 -> bf16 (finite inputs only)
    unsigned u = __float_as_uint(f);
    unsigned r = (u + 0x7fffu + ((u >> 16) & 1u)) >> 16;
    return (ushort)r;
}

// ---------------- signal kernel: zero output (signature absmax = 4.589844e-01) ----
__global__ void k_zero_out(float* __restrict__ out, int n) {
    int i = blockIdx.x * 256 + threadIdx.x;
    if (i < n) out[i] = 0.f;
}

// ---------------- Kernel A1: W1||Wq -> bf16 Wb [3072][1024] ----------------
__global__ void k_convert_w(const float* __restrict__ W1, const float* __restrict__ Wq,
                            ushort* __restrict__ Wb) {
    int i = blockIdx.x * 256 + threadIdx.x;     // float4 index, exact grid
    const int n1 = 2 * D_ * D_ / 4;             // 524288 float4s in W1
    float4 v = (i < n1) ? ((const float4*)W1)[i] : ((const float4*)Wq)[i - n1];
    ushort4 o;
    o.x = f2bf(v.x); o.y = f2bf(v.y); o.z = f2bf(v.z); o.w = f2bf(v.w);
    ((ushort4*)Wb)[i] = o;
}

// ---------------- Kernel A2: query[b][d][l] fp32 -> Xt[b][l][d] bf16 ----------------
__global__ void k_transpose(const float* __restrict__ q, ushort* __restrict__ Xt) {
    __shared__ float tile[32][33];
    int b = blockIdx.z, d0 = blockIdx.y * 32, l0 = blockIdx.x * 32;
    int tx = threadIdx.x, ty = threadIdx.y;
    const float* src = q + (size_t)b * D_ * L_;
    for (int i = 0; i < 4; i++)
        tile[ty + 8 * i][tx] = src[(size_t)(d0 + ty + 8 * i) * L_ + l0 + tx];
    __syncthreads();
    ushort* dst = Xt + (size_t)b * L_ * D_;
    for (int i = 0; i < 4; i++)
        dst[(size_t)(l0 + ty + 8 * i) * D_ + d0 + tx] = f2bf(tile[tx][ty + 8 * i]);
}

// ---------------- Kernel B: projection GEMM (MFMA) — unchanged (validated) ------
__launch_bounds__(256)
__global__ void k_proj(const ushort* __restrict__ Wb, const ushort* __restrict__ Xt,
                       ushort* __restrict__ Qb, ushort* __restrict__ Kb,
                       ushort* __restrict__ Vt) {
    __shared__ alignas(16) ushort As[128][72];   // [o][k], +8 pad
    __shared__ alignas(16) ushort Bs[128][72];   // [l][k]
    const int b  = blockIdx.z;
    const int o0 = blockIdx.y * 128;
    const int l0 = blockIdx.x * 128;
    const int t = threadIdx.x;
    const int wave = t >> 6, lane = t & 63, quad = lane >> 4, li = lane & 15;
    const int wm = wave >> 1, wn = wave & 1;
    const ushort* Xb = Xt + (size_t)b * L_ * D_;
    f32x4 acc[4][4] = {};
    const int row = t >> 3;     // 0..31
    const int chunk = t & 7;    // 0..7 (8 bf16 each)

    for (int k0 = 0; k0 < D_; k0 += 64) {
        for (int i = 0; i < 4; i++) {
            int r = row + 32 * i;
            *(float4*)&As[r][chunk * 8] = *(const float4*)&Wb[(size_t)(o0 + r) * D_ + k0 + chunk * 8];
            *(float4*)&Bs[r][chunk * 8] = *(const float4*)&Xb[(size_t)(l0 + r) * D_ + k0 + chunk * 8];
        }
        __syncthreads();
        for (int ks = 0; ks < 64; ks += 32) {
            bf16x8 af[4], bfr[4];
            for (int mf = 0; mf < 4; mf++) af[mf]  = *(const bf16x8*)&As[wm * 64 + mf * 16 + li][ks + quad * 8];
            for (int nf = 0; nf < 4; nf++) bfr[nf] = *(const bf16x8*)&Bs[wn * 64 + nf * 16 + li][ks + quad * 8];
            for (int mf = 0; mf < 4; mf++)
                for (int nf = 0; nf < 4; nf++)
                    acc[mf][nf] = __builtin_amdgcn_mfma_f32_16x16x32_bf16(af[mf], bfr[nf], acc[mf][nf], 0, 0, 0);
        }
        __syncthreads();
    }

    const int type = o0 >> 10;              // 0=K 1=V 2=Q (tile never crosses)
    const float qscale = 0.08838834764831845f;  // HD^-0.5
    for (int mf = 0; mf < 4; mf++) {
        int o = o0 + wm * 64 + mf * 16 + quad * 4;  // v[r] is channel o+r
        int c = o & 1023;
        int h = c >> 7, hd = c & 127;
        for (int nf = 0; nf < 4; nf++) {
            int l = l0 + wn * 64 + nf * 16 + li;
            f32x4 v = acc[mf][nf];
            if (type == 0) {
                ushort4 s4 = { f2bf(v[0]), f2bf(v[1]), f2bf(v[2]), f2bf(v[3]) };
                *(ushort4*)&Kb[(((size_t)(b * H_ + h)) * L_ + l) * HD_ + hd] = s4;
            } else if (type == 1) {
                size_t base = (size_t)(b * H_ + h) * HD_;
                Vt[(base + hd + 0) * L_ + l] = f2bf(v[0]);
                Vt[(base + hd + 1) * L_ + l] = f2bf(v[1]);
                Vt[(base + hd + 2) * L_ + l] = f2bf(v[2]);
                Vt[(base + hd + 3) * L_ + l] = f2bf(v[3]);
            } else {
                ushort4 s4 = { f2bf(v[0] * qscale), f2bf(v[1] * qscale),
                               f2bf(v[2] * qscale), f2bf(v[3] * qscale) };
                *(ushort4*)&Qb[(((size_t)(b * H_ + h)) * L_ + l) * HD_ + hd] = s4;
            }
        }
    }
}

// ---------------- Kernel C: flash attention (MFMA, transposed-S softmax) --------
// block = (b, h, 128 q); 4 waves x 32 q; key blocks of 64.
// S^T = K(A) x Q^T(B): keys on C rows (quad*4+r) -> softmax = 15 in-reg ops + 2 shfls.
// Mask = additive -1e30 bias staged in LDS (exactly the reference formula).
__launch_bounds__(256)
__global__ void k_attn(const ushort* __restrict__ Qb, const ushort* __restrict__ Kb,
                       const ushort* __restrict__ Vt, const int* __restrict__ mask,
                       float* __restrict__ out) {
    __shared__ alignas(16) ushort Pl[4][32][72];   // per-wave P scratch [q][key], +8 pad
    __shared__ alignas(16) float bias[L_];         // additive mask bias (8 KB)
    const int qt = blockIdx.x, h = blockIdx.y, b = blockIdx.z;
    const int t = threadIdx.x;
    const int w = t >> 6, lane = t & 63, quad = lane >> 4, li = lane & 15;
    const int q0 = qt * 128 + w * 32;
    const ushort* Qh = Qb + (size_t)(b * H_ + h) * L_ * HD_;
    const ushort* Kh = Kb + (size_t)(b * H_ + h) * L_ * HD_;
    const ushort* Vh = Vt + (size_t)(b * H_ + h) * HD_ * L_;
    const int* mb = mask + b * L_;

    // stage additive mask bias once per block
    for (int i = t; i < L_; i += 256) bias[i] = mb[i] ? 0.f : -1e30f;
    __syncthreads();

    // Q as B-fragments: qf[nq][kf] -> B[k=hd][n=q], lane: n=li, k=quad*8+j
    bf16x8 qf[2][4];
    for (int nq = 0; nq < 2; nq++)
        for (int kf = 0; kf < 4; kf++)
            qf[nq][kf] = *(const bf16x8*)&Qh[(size_t)(q0 + nq * 16 + li) * HD_ + kf * 32 + quad * 8];

    float mrun[2] = { -1e30f, -1e30f }, lrun[2] = { 0.f, 0.f };
    f32x4 acc[2][8] = {};   // PV C-layout: row q = quad*4+r (+16*nq), col hd = li (+16*nf2)

    for (int n0 = 0; n0 < L_; n0 += 64) {
        // S^T[key][q]: A = K (m=key), B = Q^T (n=q). s[nq][mt][r]: key = mt*16+quad*4+r, q = nq*16+li
        f32x4 s[2][4] = {};
        for (int kf = 0; kf < 4; kf++) {
            bf16x8 kfr[4];
            for (int mt = 0; mt < 4; mt++)
                kfr[mt] = *(const bf16x8*)&Kh[(size_t)(n0 + mt * 16 + li) * HD_ + kf * 32 + quad * 8];
            for (int mt = 0; mt < 4; mt++)
                for (int nq = 0; nq < 2; nq++)
                    s[nq][mt] = __builtin_amdgcn_mfma_f32_16x16x32_bf16(kfr[mt], qf[nq][kf], s[nq][mt], 0, 0, 0);
        }

        // additive mask bias (one b128 per key-tile)
        f32x4 bv[4];
        for (int mt = 0; mt < 4; mt++)
            bv[mt] = *(const f32x4*)&bias[n0 + mt * 16 + quad * 4];
        for (int nq = 0; nq < 2; nq++)
            for (int mt = 0; mt < 4; mt++)
                for (int r = 0; r < 4; r++)
                    s[nq][mt][r] += bv[mt][r];

        for (int nq = 0; nq < 2; nq++) {
            // max over 16 in-lane keys, then 2 shfls across quads
            float a0 = fmaxf(fmaxf(s[nq][0][0], s[nq][0][1]), fmaxf(s[nq][0][2], s[nq][0][3]));
            float a1 = fmaxf(fmaxf(s[nq][1][0], s[nq][1][1]), fmaxf(s[nq][1][2], s[nq][1][3]));
            float a2 = fmaxf(fmaxf(s[nq][2][0], s[nq][2][1]), fmaxf(s[nq][2][2], s[nq][2][3]));
            float a3 = fmaxf(fmaxf(s[nq][3][0], s[nq][3][1]), fmaxf(s[nq][3][2], s[nq][3][3]));
            float nm = fmaxf(fmaxf(a0, a1), fmaxf(a2, a3));
            nm = fmaxf(nm, __shfl_xor(nm, 16, 64));
            nm = fmaxf(nm, __shfl_xor(nm, 32, 64));
            float mnew = fmaxf(mrun[nq], nm);
            float alpha = __expf(mrun[nq] - mnew);
            mrun[nq] = mnew;
            float rs = 0.f;
            for (int mt = 0; mt < 4; mt++)
                for (int r = 0; r < 4; r++) {
                    float p = __expf(s[nq][mt][r] - mnew);
                    s[nq][mt][r] = p;
                    rs += p;
                }
            rs += __shfl_xor(rs, 16, 64);
            rs += __shfl_xor(rs, 32, 64);
            lrun[nq] = lrun[nq] * alpha + rs;
            // redistribute alpha from col-space (q=li) to row-space (q=quad*4+r): 4 parallel shfls
            int sb = (lane & 48) | (quad * 4);
            float ar0 = __shfl(alpha, sb + 0, 64);
            float ar1 = __shfl(alpha, sb + 1, 64);
            float ar2 = __shfl(alpha, sb + 2, 64);
            float ar3 = __shfl(alpha, sb + 3, 64);
            for (int nf2 = 0; nf2 < 8; nf2++) {
                acc[nq][nf2][0] *= ar0;
                acc[nq][nf2][1] *= ar1;
                acc[nq][nf2][2] *= ar2;
                acc[nq][nf2][3] *= ar3;
            }
            // P write: Pl[q = nq*16+li][key = mt*16+quad*4 + r] -- one b64 per mt
            for (int mt = 0; mt < 4; mt++) {
                ushort4 pk = { f2bf(s[nq][mt][0]), f2bf(s[nq][mt][1]),
                               f2bf(s[nq][mt][2]), f2bf(s[nq][mt][3]) };
                *(ushort4*)&Pl[w][nq * 16 + li][mt * 16 + quad * 4] = pk;
            }
        }

        // PV: A = P (m=q, from per-wave LDS), B = Vt[hd][l] (n=hd, k=key contiguous)
        for (int kf2 = 0; kf2 < 2; kf2++) {
            bf16x8 pa[2];
            for (int nq = 0; nq < 2; nq++)
                pa[nq] = *(const bf16x8*)&Pl[w][nq * 16 + li][kf2 * 32 + quad * 8];
            for (int nf2 = 0; nf2 < 8; nf2++) {
                bf16x8 vb = *(const bf16x8*)&Vh[(size_t)(nf2 * 16 + li) * L_ + n0 + kf2 * 32 + quad * 8];
                for (int nq = 0; nq < 2; nq++)
                    acc[nq][nf2] = __builtin_amdgcn_mfma_f32_16x16x32_bf16(pa[nq], vb, acc[nq][nf2], 0, 0, 0);
            }
        }
    }

    // epilogue: redistribute 1/l to row-space, float4 stores (4 consecutive l)
    for (int nq = 0; nq < 2; nq++) {
        float inv = 1.0f / lrun[nq];
        int sb = (lane & 48) | (quad * 4);
        float i0 = __shfl(inv, sb + 0, 64);
        float i1 = __shfl(inv, sb + 1, 64);
        float i2 = __shfl(inv, sb + 2, 64);
        float i3 = __shfl(inv, sb + 3, 64);
        int l = q0 + nq * 16 + quad * 4;
        for (int nf2 = 0; nf2 < 8; nf2++) {
            int d = h * HD_ + nf2 * 16 + li;
            float4 o4 = { acc[nq][nf2][0] * i0, acc[nq][nf2][1] * i1,
                          acc[nq][nf2][2] * i2, acc[nq][nf2][3] * i3 };
            *(float4*)&out[((size_t)(b * D_ + d)) * L_ + l] = o4;
        }
    }
}

extern "C" void kernel_launch(void* const* d_in, const int* in_sizes, int n_in,
                              void* d_out, int out_size, void* d_ws, size_t ws_size,
                              hipStream_t stream) {
    // Bind inputs by element count (all distinct).
    const float* query = nullptr;  // 4*1024*2048 = 8388608
    const int*   mask  = nullptr;  // 4*2048     = 8192
    const float* W1    = nullptr;  // 2048*1024  = 2097152
    const float* Wq    = nullptr;  // 1024*1024  = 1048576
    for (int i = 0; i < n_in; i++) {
        switch (in_sizes[i]) {
            case 8388608: query = (const float*)d_in[i]; break;
            case 8192:    mask  = (const int*)d_in[i];   break;
            case 2097152: W1    = (const float*)d_in[i]; break;
            case 1048576: Wq    = (const float*)d_in[i]; break;
        }
    }
    float* out = (float*)d_out;  // [4,1024,2048] fp32 (reference output dtype)

    if (ws_size < 50331648u || !query || !mask || !W1 || !Wq) {
        hipLaunchKernelGGL(k_zero_out, dim3((out_size + 255) / 256), dim3(256), 0, stream,
                           out, out_size);
        return;
    }

    // d_out (32 MB fp32) is dead until k_attn -> use its head as projection scratch.
    ushort* Wb = (ushort*)d_out;                       // [3072][1024]      6291456 B
    ushort* Xt = (ushort*)((char*)d_out + 6291456);    // [4][2048][1024]  16777216 B
    char* ws = (char*)d_ws;                            // Qb|Kb|Vt = 48 MB <= gate
    ushort* Qb = (ushort*)(ws + 0);
    ushort* Kb = (ushort*)(ws + 16777216);
    ushort* Vt = (ushort*)(ws + 33554432);

    hipLaunchKernelGGL(k_convert_w, dim3(3072), dim3(256), 0, stream, W1, Wq, Wb);
    hipLaunchKernelGGL(k_transpose, dim3(64, 32, 4), dim3(32, 8), 0, stream, query, Xt);
    hipLaunchKernelGGL(k_proj, dim3(16, 24, 4), dim3(256), 0, stream, Wb, Xt, Qb, Kb, Vt);
    hipLaunchKernelGGL(k_attn, dim3(16, 8, 4), dim3(256), 0, stream, Qb, Kb, Vt, mask, out);
}

// Round 8
// 459.138 us; speedup vs baseline: 1.2555x; 1.2555x over previous
//
#include <hip/hip_runtime.h>
#include <hip/hip_bf16.h>

#define B_  4
#define D_  1024
#define L_  2048
#define H_  8
#define HD_ 128

typedef __attribute__((ext_vector_type(8))) short bf16x8;
typedef __attribute__((ext_vector_type(4))) float f32x4;

static __device__ __forceinline__ ushort f2bf(float f) {
    // round-to-nearest-even fp32 -> bf16 (finite inputs only)
    unsigned u = __float_as_uint(f);
    unsigned r = (u + 0x7fffu + ((u >> 16) & 1u)) >> 16;
    return (ushort)r;
}

// ---------------- signal kernel: zero output (signature absmax = 4.589844e-01) ----
__global__ void k_zero_out(float* __restrict__ out, int n) {
    int i = blockIdx.x * 256 + threadIdx.x;
    if (i < n) out[i] = 0.f;
}

// ---------------- Kernel A1: W1||Wq -> bf16 Wb [3072][1024] ----------------
__global__ void k_convert_w(const float* __restrict__ W1, const float* __restrict__ Wq,
                            ushort* __restrict__ Wb) {
    int i = blockIdx.x * 256 + threadIdx.x;     // float4 index, exact grid
    const int n1 = 2 * D_ * D_ / 4;             // 524288 float4s in W1
    float4 v = (i < n1) ? ((const float4*)W1)[i] : ((const float4*)Wq)[i - n1];
    ushort4 o;
    o.x = f2bf(v.x); o.y = f2bf(v.y); o.z = f2bf(v.z); o.w = f2bf(v.w);
    ((ushort4*)Wb)[i] = o;
}

// ---------------- Kernel A2: query[b][d][l] fp32 -> Xt[b][l][d] bf16 ----------------
__global__ void k_transpose(const float* __restrict__ q, ushort* __restrict__ Xt) {
    __shared__ float tile[32][33];
    int b = blockIdx.z, d0 = blockIdx.y * 32, l0 = blockIdx.x * 32;
    int tx = threadIdx.x, ty = threadIdx.y;
    const float* src = q + (size_t)b * D_ * L_;
    for (int i = 0; i < 4; i++)
        tile[ty + 8 * i][tx] = src[(size_t)(d0 + ty + 8 * i) * L_ + l0 + tx];
    __syncthreads();
    ushort* dst = Xt + (size_t)b * L_ * D_;
    for (int i = 0; i < 4; i++)
        dst[(size_t)(l0 + ty + 8 * i) * D_ + d0 + tx] = f2bf(tile[tx][ty + 8 * i]);
}

// ---------------- Kernel B: projection GEMM (MFMA) — unchanged (validated) ------
__launch_bounds__(256)
__global__ void k_proj(const ushort* __restrict__ Wb, const ushort* __restrict__ Xt,
                       ushort* __restrict__ Qb, ushort* __restrict__ Kb,
                       ushort* __restrict__ Vt) {
    __shared__ alignas(16) ushort As[128][72];   // [o][k], +8 pad
    __shared__ alignas(16) ushort Bs[128][72];   // [l][k]
    const int b  = blockIdx.z;
    const int o0 = blockIdx.y * 128;
    const int l0 = blockIdx.x * 128;
    const int t = threadIdx.x;
    const int wave = t >> 6, lane = t & 63, quad = lane >> 4, li = lane & 15;
    const int wm = wave >> 1, wn = wave & 1;
    const ushort* Xb = Xt + (size_t)b * L_ * D_;
    f32x4 acc[4][4] = {};
    const int row = t >> 3;     // 0..31
    const int chunk = t & 7;    // 0..7 (8 bf16 each)

    for (int k0 = 0; k0 < D_; k0 += 64) {
        for (int i = 0; i < 4; i++) {
            int r = row + 32 * i;
            *(float4*)&As[r][chunk * 8] = *(const float4*)&Wb[(size_t)(o0 + r) * D_ + k0 + chunk * 8];
            *(float4*)&Bs[r][chunk * 8] = *(const float4*)&Xb[(size_t)(l0 + r) * D_ + k0 + chunk * 8];
        }
        __syncthreads();
        for (int ks = 0; ks < 64; ks += 32) {
            bf16x8 af[4], bfr[4];
            for (int mf = 0; mf < 4; mf++) af[mf]  = *(const bf16x8*)&As[wm * 64 + mf * 16 + li][ks + quad * 8];
            for (int nf = 0; nf < 4; nf++) bfr[nf] = *(const bf16x8*)&Bs[wn * 64 + nf * 16 + li][ks + quad * 8];
            for (int mf = 0; mf < 4; mf++)
                for (int nf = 0; nf < 4; nf++)
                    acc[mf][nf] = __builtin_amdgcn_mfma_f32_16x16x32_bf16(af[mf], bfr[nf], acc[mf][nf], 0, 0, 0);
        }
        __syncthreads();
    }

    const int type = o0 >> 10;              // 0=K 1=V 2=Q (tile never crosses)
    const float qscale = 0.08838834764831845f;  // HD^-0.5
    for (int mf = 0; mf < 4; mf++) {
        int o = o0 + wm * 64 + mf * 16 + quad * 4;  // v[r] is channel o+r
        int c = o & 1023;
        int h = c >> 7, hd = c & 127;
        for (int nf = 0; nf < 4; nf++) {
            int l = l0 + wn * 64 + nf * 16 + li;
            f32x4 v = acc[mf][nf];
            if (type == 0) {
                ushort4 s4 = { f2bf(v[0]), f2bf(v[1]), f2bf(v[2]), f2bf(v[3]) };
                *(ushort4*)&Kb[(((size_t)(b * H_ + h)) * L_ + l) * HD_ + hd] = s4;
            } else if (type == 1) {
                size_t base = (size_t)(b * H_ + h) * HD_;
                Vt[(base + hd + 0) * L_ + l] = f2bf(v[0]);
                Vt[(base + hd + 1) * L_ + l] = f2bf(v[1]);
                Vt[(base + hd + 2) * L_ + l] = f2bf(v[2]);
                Vt[(base + hd + 3) * L_ + l] = f2bf(v[3]);
            } else {
                ushort4 s4 = { f2bf(v[0] * qscale), f2bf(v[1] * qscale),
                               f2bf(v[2] * qscale), f2bf(v[3] * qscale) };
                *(ushort4*)&Qb[(((size_t)(b * H_ + h)) * L_ + l) * HD_ + hd] = s4;
            }
        }
    }
}

// ---------------- Kernel C: flash attention (MFMA, LDS-staged K/V) --------------
// block = (b, h, 128 q); 4 waves x 32 q; key blocks of 64.
// K/V tiles staged cooperatively into LDS (XOR-swizzled addrs), shared by all waves.
// 1-D grid with XCD swizzle: blk = h + 8*(qt + 16*b) -> one head-index per XCD.
__launch_bounds__(256)
__global__ void k_attn(const ushort* __restrict__ Qb, const ushort* __restrict__ Kb,
                       const ushort* __restrict__ Vt, const int* __restrict__ mask,
                       float* __restrict__ out) {
    __shared__ alignas(16) ushort Ks[64][128];     // [key][hd-chunk swizzled] 16 KB
    __shared__ alignas(16) ushort Vs[128][64];     // [hd][key-chunk swizzled] 16 KB
    __shared__ alignas(16) ushort Pl[4][32][72];   // per-wave P scratch [q][key], +8 pad
    __shared__ alignas(16) float bias[L_];         // additive mask bias (8 KB)
    const int blk = blockIdx.x;
    const int h = blk & 7, qt = (blk >> 3) & 15, b = blk >> 7;
    const int t = threadIdx.x;
    const int w = t >> 6, lane = t & 63, quad = lane >> 4, li = lane & 15;
    const int q0 = qt * 128 + w * 32;
    const ushort* Qh = Qb + (size_t)(b * H_ + h) * L_ * HD_;
    const ushort* Kh = Kb + (size_t)(b * H_ + h) * L_ * HD_;
    const ushort* Vh = Vt + (size_t)(b * H_ + h) * HD_ * L_;
    const int* mb = mask + b * L_;

    // stage additive mask bias once (covered by first in-loop barrier)
    for (int i = t; i < L_; i += 256) bias[i] = mb[i] ? 0.f : -1e30f;

    // staging pointers (LDS side is n0-invariant; global side += per iter)
    const ushort* kg[4]; ushort* kl[4];
    const ushort* vg[4]; ushort* vl[4];
    for (int i = 0; i < 4; i++) {
        int rowk = w * 16 + i * 4 + (lane >> 4);      // 0..63
        int ck   = lane & 15;                          // 16B chunk in 256B row
        kg[i] = Kh + (size_t)rowk * HD_ + ck * 8;
        kl[i] = &Ks[rowk][(ck ^ (rowk & 15)) * 8];
        int hdv = w * 32 + i * 8 + (lane >> 3);       // 0..127
        int cv  = lane & 7;                            // 16B chunk in 128B row
        vg[i] = Vh + (size_t)hdv * L_ + cv * 8;
        vl[i] = &Vs[hdv][(cv ^ (hdv & 7)) * 8];
    }

    // Q as B-fragments (from global, linear): qf[nq][kf]
    bf16x8 qf[2][4];
    for (int nq = 0; nq < 2; nq++)
        for (int kf = 0; kf < 4; kf++)
            qf[nq][kf] = *(const bf16x8*)&Qh[(size_t)(q0 + nq * 16 + li) * HD_ + kf * 32 + quad * 8];

    float mrun[2] = { -1e30f, -1e30f }, lrun[2] = { 0.f, 0.f };
    f32x4 acc[2][8] = {};   // PV C-layout: row q = quad*4+r (+16*nq), col hd = li (+16*nf2)

    for (int n0 = 0; n0 < L_; n0 += 64) {
        // ---- cooperative staging: 8 batched 16B loads per wave, then LDS writes
        uint4 kt[4], vt4[4];
        for (int i = 0; i < 4; i++) kt[i]  = *(const uint4*)kg[i];
        for (int i = 0; i < 4; i++) vt4[i] = *(const uint4*)vg[i];
        for (int i = 0; i < 4; i++) *(uint4*)kl[i] = kt[i];
        for (int i = 0; i < 4; i++) *(uint4*)vl[i] = vt4[i];
        for (int i = 0; i < 4; i++) { kg[i] += 64 * HD_; vg[i] += 64; }
        __syncthreads();

        // ---- S^T = K(A) x Q^T(B): s[nq][mt][r]: key = mt*16+quad*4+r, q = nq*16+li
        f32x4 s[2][4] = {};
        for (int kf = 0; kf < 4; kf++) {
            bf16x8 kfr[4];
            for (int mt = 0; mt < 4; mt++) {
                int row = mt * 16 + li;
                kfr[mt] = *(const bf16x8*)&Ks[row][((kf * 4 + quad) ^ li) * 8];
            }
            for (int mt = 0; mt < 4; mt++)
                for (int nq = 0; nq < 2; nq++)
                    s[nq][mt] = __builtin_amdgcn_mfma_f32_16x16x32_bf16(kfr[mt], qf[nq][kf], s[nq][mt], 0, 0, 0);
        }

        // additive mask bias (one b128 per key-tile)
        f32x4 bv[4];
        for (int mt = 0; mt < 4; mt++)
            bv[mt] = *(const f32x4*)&bias[n0 + mt * 16 + quad * 4];
        for (int nq = 0; nq < 2; nq++)
            for (int mt = 0; mt < 4; mt++)
                for (int r = 0; r < 4; r++)
                    s[nq][mt][r] += bv[mt][r];

        for (int nq = 0; nq < 2; nq++) {
            float a0 = fmaxf(fmaxf(s[nq][0][0], s[nq][0][1]), fmaxf(s[nq][0][2], s[nq][0][3]));
            float a1 = fmaxf(fmaxf(s[nq][1][0], s[nq][1][1]), fmaxf(s[nq][1][2], s[nq][1][3]));
            float a2 = fmaxf(fmaxf(s[nq][2][0], s[nq][2][1]), fmaxf(s[nq][2][2], s[nq][2][3]));
            float a3 = fmaxf(fmaxf(s[nq][3][0], s[nq][3][1]), fmaxf(s[nq][3][2], s[nq][3][3]));
            float nm = fmaxf(fmaxf(a0, a1), fmaxf(a2, a3));
            nm = fmaxf(nm, __shfl_xor(nm, 16, 64));
            nm = fmaxf(nm, __shfl_xor(nm, 32, 64));
            float mnew = fmaxf(mrun[nq], nm);
            float alpha = __expf(mrun[nq] - mnew);
            mrun[nq] = mnew;
            float rs = 0.f;
            for (int mt = 0; mt < 4; mt++)
                for (int r = 0; r < 4; r++) {
                    float p = __expf(s[nq][mt][r] - mnew);
                    s[nq][mt][r] = p;
                    rs += p;
                }
            rs += __shfl_xor(rs, 16, 64);
            rs += __shfl_xor(rs, 32, 64);
            lrun[nq] = lrun[nq] * alpha + rs;
            // redistribute alpha from col-space (q=li) to row-space (q=quad*4+r)
            int sb = (lane & 48) | (quad * 4);
            float ar0 = __shfl(alpha, sb + 0, 64);
            float ar1 = __shfl(alpha, sb + 1, 64);
            float ar2 = __shfl(alpha, sb + 2, 64);
            float ar3 = __shfl(alpha, sb + 3, 64);
            for (int nf2 = 0; nf2 < 8; nf2++) {
                acc[nq][nf2][0] *= ar0;
                acc[nq][nf2][1] *= ar1;
                acc[nq][nf2][2] *= ar2;
                acc[nq][nf2][3] *= ar3;
            }
            // P write: Pl[q = nq*16+li][key = mt*16+quad*4 + r]
            for (int mt = 0; mt < 4; mt++) {
                ushort4 pk = { f2bf(s[nq][mt][0]), f2bf(s[nq][mt][1]),
                               f2bf(s[nq][mt][2]), f2bf(s[nq][mt][3]) };
                *(ushort4*)&Pl[w][nq * 16 + li][mt * 16 + quad * 4] = pk;
            }
        }

        // ---- PV: A = P (per-wave LDS), B = V from staged LDS [hd][key-swizzled]
        for (int kf2 = 0; kf2 < 2; kf2++) {
            bf16x8 pa[2];
            for (int nq = 0; nq < 2; nq++)
                pa[nq] = *(const bf16x8*)&Pl[w][nq * 16 + li][kf2 * 32 + quad * 8];
            for (int nf2 = 0; nf2 < 8; nf2++) {
                int row = nf2 * 16 + li;
                bf16x8 vb = *(const bf16x8*)&Vs[row][((kf2 * 4 + quad) ^ (li & 7)) * 8];
                for (int nq = 0; nq < 2; nq++)
                    acc[nq][nf2] = __builtin_amdgcn_mfma_f32_16x16x32_bf16(pa[nq], vb, acc[nq][nf2], 0, 0, 0);
            }
        }
        __syncthreads();   // guard Ks/Vs against next iteration's staging
    }

    // epilogue: redistribute 1/l to row-space, float4 stores (4 consecutive l)
    for (int nq = 0; nq < 2; nq++) {
        float inv = 1.0f / lrun[nq];
        int sb = (lane & 48) | (quad * 4);
        float i0 = __shfl(inv, sb + 0, 64);
        float i1 = __shfl(inv, sb + 1, 64);
        float i2 = __shfl(inv, sb + 2, 64);
        float i3 = __shfl(inv, sb + 3, 64);
        int l = q0 + nq * 16 + quad * 4;
        for (int nf2 = 0; nf2 < 8; nf2++) {
            int d = h * HD_ + nf2 * 16 + li;
            float4 o4 = { acc[nq][nf2][0] * i0, acc[nq][nf2][1] * i1,
                          acc[nq][nf2][2] * i2, acc[nq][nf2][3] * i3 };
            *(float4*)&out[((size_t)(b * D_ + d)) * L_ + l] = o4;
        }
    }
}

extern "C" void kernel_launch(void* const* d_in, const int* in_sizes, int n_in,
                              void* d_out, int out_size, void* d_ws, size_t ws_size,
                              hipStream_t stream) {
    // Bind inputs by element count (all distinct).
    const float* query = nullptr;  // 4*1024*2048 = 8388608
    const int*   mask  = nullptr;  // 4*2048     = 8192
    const float* W1    = nullptr;  // 2048*1024  = 2097152
    const float* Wq    = nullptr;  // 1024*1024  = 1048576
    for (int i = 0; i < n_in; i++) {
        switch (in_sizes[i]) {
            case 8388608: query = (const float*)d_in[i]; break;
            case 8192:    mask  = (const int*)d_in[i];   break;
            case 2097152: W1    = (const float*)d_in[i]; break;
            case 1048576: Wq    = (const float*)d_in[i]; break;
        }
    }
    float* out = (float*)d_out;  // [4,1024,2048] fp32 (reference output dtype)

    if (ws_size < 50331648u || !query || !mask || !W1 || !Wq) {
        hipLaunchKernelGGL(k_zero_out, dim3((out_size + 255) / 256), dim3(256), 0, stream,
                           out, out_size);
        return;
    }

    // d_out (32 MB fp32) is dead until k_attn -> use its head as projection scratch.
    ushort* Wb = (ushort*)d_out;                       // [3072][1024]      6291456 B
    ushort* Xt = (ushort*)((char*)d_out + 6291456);    // [4][2048][1024]  16777216 B
    char* ws = (char*)d_ws;                            // Qb|Kb|Vt = 48 MB <= gate
    ushort* Qb = (ushort*)(ws + 0);
    ushort* Kb = (ushort*)(ws + 16777216);
    ushort* Vt = (ushort*)(ws + 33554432);

    hipLaunchKernelGGL(k_convert_w, dim3(3072), dim3(256), 0, stream, W1, Wq, Wb);
    hipLaunchKernelGGL(k_transpose, dim3(64, 32, 4), dim3(32, 8), 0, stream, query, Xt);
    hipLaunchKernelGGL(k_proj, dim3(16, 24, 4), dim3(256), 0, stream, Wb, Xt, Qb, Kb, Vt);
    hipLaunchKernelGGL(k_attn, dim3(512), dim3(256), 0, stream, Qb, Kb, Vt, mask, out);
}

// Round 9
// 378.021 us; speedup vs baseline: 1.5249x; 1.2146x over previous
//
#include <hip/hip_runtime.h>
#include <hip/hip_bf16.h>

#define B_  4
#define D_  1024
#define L_  2048
#define H_  8
#define HD_ 128

typedef __attribute__((ext_vector_type(8))) short bf16x8;
typedef __attribute__((ext_vector_type(4))) float f32x4;

static __device__ __forceinline__ ushort f2bf(float f) {
    // round-to-nearest-even fp32 -> bf16 (finite inputs only)
    unsigned u = __float_as_uint(f);
    unsigned r = (u + 0x7fffu + ((u >> 16) & 1u)) >> 16;
    return (ushort)r;
}

// async 16B global->LDS DMA (dest = wave-uniform LDS base + lane*16)
static __device__ __forceinline__ void dma16(const ushort* g, ushort* l) {
    __builtin_amdgcn_global_load_lds(
        (const __attribute__((address_space(1))) void*)g,
        (__attribute__((address_space(3))) void*)l, 16, 0, 0);
}

// ---------------- signal kernel: zero output (signature absmax = 4.589844e-01) ----
__global__ void k_zero_out(float* __restrict__ out, int n) {
    int i = blockIdx.x * 256 + threadIdx.x;
    if (i < n) out[i] = 0.f;
}

// ---------------- Kernel A1: W1||Wq -> bf16 Wb [3072][1024] ----------------
__global__ void k_convert_w(const float* __restrict__ W1, const float* __restrict__ Wq,
                            ushort* __restrict__ Wb) {
    int i = blockIdx.x * 256 + threadIdx.x;     // float4 index, exact grid
    const int n1 = 2 * D_ * D_ / 4;             // 524288 float4s in W1
    float4 v = (i < n1) ? ((const float4*)W1)[i] : ((const float4*)Wq)[i - n1];
    ushort4 o;
    o.x = f2bf(v.x); o.y = f2bf(v.y); o.z = f2bf(v.z); o.w = f2bf(v.w);
    ((ushort4*)Wb)[i] = o;
}

// ---------------- Kernel A2: query[b][d][l] fp32 -> Xt[b][l][d] bf16 ----------------
__global__ void k_transpose(const float* __restrict__ q, ushort* __restrict__ Xt) {
    __shared__ float tile[32][33];
    int b = blockIdx.z, d0 = blockIdx.y * 32, l0 = blockIdx.x * 32;
    int tx = threadIdx.x, ty = threadIdx.y;
    const float* src = q + (size_t)b * D_ * L_;
    for (int i = 0; i < 4; i++)
        tile[ty + 8 * i][tx] = src[(size_t)(d0 + ty + 8 * i) * L_ + l0 + tx];
    __syncthreads();
    ushort* dst = Xt + (size_t)b * L_ * D_;
    for (int i = 0; i < 4; i++)
        dst[(size_t)(l0 + ty + 8 * i) * D_ + d0 + tx] = f2bf(tile[tx][ty + 8 * i]);
}

// ---------------- Kernel B: projection GEMM (MFMA) — unchanged (validated) ------
__launch_bounds__(256)
__global__ void k_proj(const ushort* __restrict__ Wb, const ushort* __restrict__ Xt,
                       ushort* __restrict__ Qb, ushort* __restrict__ Kb,
                       ushort* __restrict__ Vt) {
    __shared__ alignas(16) ushort As[128][72];   // [o][k], +8 pad
    __shared__ alignas(16) ushort Bs[128][72];   // [l][k]
    const int b  = blockIdx.z;
    const int o0 = blockIdx.y * 128;
    const int l0 = blockIdx.x * 128;
    const int t = threadIdx.x;
    const int wave = t >> 6, lane = t & 63, quad = lane >> 4, li = lane & 15;
    const int wm = wave >> 1, wn = wave & 1;
    const ushort* Xb = Xt + (size_t)b * L_ * D_;
    f32x4 acc[4][4] = {};
    const int row = t >> 3;     // 0..31
    const int chunk = t & 7;    // 0..7 (8 bf16 each)

    for (int k0 = 0; k0 < D_; k0 += 64) {
        for (int i = 0; i < 4; i++) {
            int r = row + 32 * i;
            *(float4*)&As[r][chunk * 8] = *(const float4*)&Wb[(size_t)(o0 + r) * D_ + k0 + chunk * 8];
            *(float4*)&Bs[r][chunk * 8] = *(const float4*)&Xb[(size_t)(l0 + r) * D_ + k0 + chunk * 8];
        }
        __syncthreads();
        for (int ks = 0; ks < 64; ks += 32) {
            bf16x8 af[4], bfr[4];
            for (int mf = 0; mf < 4; mf++) af[mf]  = *(const bf16x8*)&As[wm * 64 + mf * 16 + li][ks + quad * 8];
            for (int nf = 0; nf < 4; nf++) bfr[nf] = *(const bf16x8*)&Bs[wn * 64 + nf * 16 + li][ks + quad * 8];
            for (int mf = 0; mf < 4; mf++)
                for (int nf = 0; nf < 4; nf++)
                    acc[mf][nf] = __builtin_amdgcn_mfma_f32_16x16x32_bf16(af[mf], bfr[nf], acc[mf][nf], 0, 0, 0);
        }
        __syncthreads();
    }

    const int type = o0 >> 10;              // 0=K 1=V 2=Q (tile never crosses)
    const float qscale = 0.08838834764831845f;  // HD^-0.5
    for (int mf = 0; mf < 4; mf++) {
        int o = o0 + wm * 64 + mf * 16 + quad * 4;  // v[r] is channel o+r
        int c = o & 1023;
        int h = c >> 7, hd = c & 127;
        for (int nf = 0; nf < 4; nf++) {
            int l = l0 + wn * 64 + nf * 16 + li;
            f32x4 v = acc[mf][nf];
            if (type == 0) {
                ushort4 s4 = { f2bf(v[0]), f2bf(v[1]), f2bf(v[2]), f2bf(v[3]) };
                *(ushort4*)&Kb[(((size_t)(b * H_ + h)) * L_ + l) * HD_ + hd] = s4;
            } else if (type == 1) {
                size_t base = (size_t)(b * H_ + h) * HD_;
                Vt[(base + hd + 0) * L_ + l] = f2bf(v[0]);
                Vt[(base + hd + 1) * L_ + l] = f2bf(v[1]);
                Vt[(base + hd + 2) * L_ + l] = f2bf(v[2]);
                Vt[(base + hd + 3) * L_ + l] = f2bf(v[3]);
            } else {
                ushort4 s4 = { f2bf(v[0] * qscale), f2bf(v[1] * qscale),
                               f2bf(v[2] * qscale), f2bf(v[3] * qscale) };
                *(ushort4*)&Qb[(((size_t)(b * H_ + h)) * L_ + l) * HD_ + hd] = s4;
            }
        }
    }
}

// ---------------- Kernel C: flash attention (MFMA, async-DMA double-buffered K/V) ---
// block = (b, h, 128 q); 4 waves x 32 q; key blocks of 64; ONE barrier per iteration.
// DMA for tile i+1 issued right after the top barrier, completes during compute.
// XOR bank-swizzle realized via the DMA gptr permutation (LDS dest is lane-linear).
__launch_bounds__(256)
__global__ void k_attn(const ushort* __restrict__ Qb, const ushort* __restrict__ Kb,
                       const ushort* __restrict__ Vt, const int* __restrict__ mask,
                       float* __restrict__ out) {
    __shared__ alignas(16) ushort Ks[2][64][128];   // 32 KB [buf][key][hd-chunk swizzled]
    __shared__ alignas(16) ushort Vs[2][128][64];   // 32 KB [buf][hd][key-chunk swizzled]
    __shared__ alignas(16) ushort Pl[4][16][72];    // 9 KB per-wave P scratch [q][key]
    const int blk = blockIdx.x;
    const int h = blk & 7, qt = (blk >> 3) & 15, b = blk >> 7;
    const int t = threadIdx.x;
    const int w = t >> 6, lane = t & 63, quad = lane >> 4, li = lane & 15;
    const int q0 = qt * 128 + w * 32;
    const ushort* Qh = Qb + (size_t)(b * H_ + h) * L_ * HD_;
    const ushort* Kh = Kb + (size_t)(b * H_ + h) * L_ * HD_;
    const ushort* Vh = Vt + (size_t)(b * H_ + h) * HD_ * L_;
    const int* mb = mask + b * L_;

    // DMA source pointers (lane-dependent; per-tile offset added at issue).
    // K slot (key, p) holds global chunk p ^ (key&15); lane l -> key=seg*4+(l>>4), p=l&15.
    // V slot (hd, p)  holds global chunk p ^ (hd&7);   lane l -> hd=seg*8+(l>>3),  p=l&7.
    const ushort* kgp[4]; const ushort* vgp[4];
    for (int i = 0; i < 4; i++) {
        int seg = w * 4 + i;
        int key = seg * 4 + (lane >> 4);
        int ck  = (lane & 15) ^ (key & 15);
        kgp[i] = Kh + (size_t)key * HD_ + ck * 8;
        int hd  = seg * 8 + (lane >> 3);
        int cv  = (lane & 7) ^ (hd & 7);
        vgp[i] = Vh + (size_t)hd * L_ + cv * 8;
    }

    // prologue: DMA tile 0 into buf 0 (1 KB per wave per call)
    for (int i = 0; i < 4; i++) dma16(kgp[i], &Ks[0][0][0] + (w * 4 + i) * 512);
    for (int i = 0; i < 4; i++) dma16(vgp[i], &Vs[0][0][0] + (w * 4 + i) * 512);

    // Q as B-fragments (global, linear): qf[nq][kf]
    bf16x8 qf[2][4];
    for (int nq = 0; nq < 2; nq++)
        for (int kf = 0; kf < 4; kf++)
            qf[nq][kf] = *(const bf16x8*)&Qh[(size_t)(q0 + nq * 16 + li) * HD_ + kf * 32 + quad * 8];

    float mrun[2] = { -1e30f, -1e30f }, lrun[2] = { 0.f, 0.f };
    f32x4 acc[2][8] = {};   // PV C-layout: row q = quad*4+r (+16*nq), col hd = li (+16*nf2)

    int buf = 0;
    for (int n0 = 0; n0 < L_; n0 += 64, buf ^= 1) {
        __syncthreads();   // buf's DMA drained+visible; all waves past prior buf reads

        if (n0 + 64 < L_) {  // uniform branch: issue next tile's DMA into other buffer
            int nb = buf ^ 1;
            for (int i = 0; i < 4; i++)
                dma16(kgp[i] + (size_t)(n0 + 64) * HD_, &Ks[nb][0][0] + (w * 4 + i) * 512);
            for (int i = 0; i < 4; i++)
                dma16(vgp[i] + (n0 + 64), &Vs[nb][0][0] + (w * 4 + i) * 512);
        }

        // mask -> additive bias (L2-hot int4 loads)
        f32x4 bv[4];
        for (int mt = 0; mt < 4; mt++) {
            int4 mk = *(const int4*)&mb[n0 + mt * 16 + quad * 4];
            bv[mt][0] = mk.x ? 0.f : -1e30f;
            bv[mt][1] = mk.y ? 0.f : -1e30f;
            bv[mt][2] = mk.z ? 0.f : -1e30f;
            bv[mt][3] = mk.w ? 0.f : -1e30f;
        }

        // S^T = K(A) x Q^T(B): s[nq][mt][r]: key = mt*16+quad*4+r, q = nq*16+li
        f32x4 s[2][4] = {};
        for (int kf = 0; kf < 4; kf++) {
            bf16x8 kfr[4];
            for (int mt = 0; mt < 4; mt++)
                kfr[mt] = *(const bf16x8*)&Ks[buf][mt * 16 + li][((kf * 4 + quad) ^ li) * 8];
            for (int mt = 0; mt < 4; mt++)
                for (int nq = 0; nq < 2; nq++)
                    s[nq][mt] = __builtin_amdgcn_mfma_f32_16x16x32_bf16(kfr[mt], qf[nq][kf], s[nq][mt], 0, 0, 0);
        }
        for (int nq = 0; nq < 2; nq++)
            for (int mt = 0; mt < 4; mt++)
                for (int r = 0; r < 4; r++)
                    s[nq][mt][r] += bv[mt][r];

        for (int nq = 0; nq < 2; nq++) {
            float a0 = fmaxf(fmaxf(s[nq][0][0], s[nq][0][1]), fmaxf(s[nq][0][2], s[nq][0][3]));
            float a1 = fmaxf(fmaxf(s[nq][1][0], s[nq][1][1]), fmaxf(s[nq][1][2], s[nq][1][3]));
            float a2 = fmaxf(fmaxf(s[nq][2][0], s[nq][2][1]), fmaxf(s[nq][2][2], s[nq][2][3]));
            float a3 = fmaxf(fmaxf(s[nq][3][0], s[nq][3][1]), fmaxf(s[nq][3][2], s[nq][3][3]));
            float nm = fmaxf(fmaxf(a0, a1), fmaxf(a2, a3));
            nm = fmaxf(nm, __shfl_xor(nm, 16, 64));
            nm = fmaxf(nm, __shfl_xor(nm, 32, 64));
            float mnew = fmaxf(mrun[nq], nm);
            float alpha = __expf(mrun[nq] - mnew);
            mrun[nq] = mnew;
            float rs = 0.f;
            for (int mt = 0; mt < 4; mt++)
                for (int r = 0; r < 4; r++) {
                    float p = __expf(s[nq][mt][r] - mnew);
                    s[nq][mt][r] = p;
                    rs += p;
                }
            rs += __shfl_xor(rs, 16, 64);
            rs += __shfl_xor(rs, 32, 64);
            lrun[nq] = lrun[nq] * alpha + rs;
            // alpha: col-space (q=li) -> row-space (q=quad*4+r), 4 parallel shfls
            int sb = (lane & 48) | (quad * 4);
            float ar0 = __shfl(alpha, sb + 0, 64);
            float ar1 = __shfl(alpha, sb + 1, 64);
            float ar2 = __shfl(alpha, sb + 2, 64);
            float ar3 = __shfl(alpha, sb + 3, 64);
            for (int nf2 = 0; nf2 < 8; nf2++) {
                acc[nq][nf2][0] *= ar0;
                acc[nq][nf2][1] *= ar1;
                acc[nq][nf2][2] *= ar2;
                acc[nq][nf2][3] *= ar3;
            }
            // P write (per-wave half-buffer): Pl[w][q=li][key = mt*16+quad*4+r]
            for (int mt = 0; mt < 4; mt++) {
                ushort4 pk = { f2bf(s[nq][mt][0]), f2bf(s[nq][mt][1]),
                               f2bf(s[nq][mt][2]), f2bf(s[nq][mt][3]) };
                *(ushort4*)&Pl[w][li][mt * 16 + quad * 4] = pk;
            }
            // PV for this nq: A = P (LDS), B = V from staged LDS
            for (int kf2 = 0; kf2 < 2; kf2++) {
                bf16x8 pa = *(const bf16x8*)&Pl[w][li][kf2 * 32 + quad * 8];
                for (int nf2 = 0; nf2 < 8; nf2++) {
                    bf16x8 vb = *(const bf16x8*)&Vs[buf][nf2 * 16 + li][((kf2 * 4 + quad) ^ (li & 7)) * 8];
                    acc[nq][nf2] = __builtin_amdgcn_mfma_f32_16x16x32_bf16(pa, vb, acc[nq][nf2], 0, 0, 0);
                }
            }
        }
    }

    // epilogue: redistribute 1/l to row-space, float4 stores (4 consecutive l)
    for (int nq = 0; nq < 2; nq++) {
        float inv = 1.0f / lrun[nq];
        int sb = (lane & 48) | (quad * 4);
        float i0 = __shfl(inv, sb + 0, 64);
        float i1 = __shfl(inv, sb + 1, 64);
        float i2 = __shfl(inv, sb + 2, 64);
        float i3 = __shfl(inv, sb + 3, 64);
        int l = q0 + nq * 16 + quad * 4;
        for (int nf2 = 0; nf2 < 8; nf2++) {
            int d = h * HD_ + nf2 * 16 + li;
            float4 o4 = { acc[nq][nf2][0] * i0, acc[nq][nf2][1] * i1,
                          acc[nq][nf2][2] * i2, acc[nq][nf2][3] * i3 };
            *(float4*)&out[((size_t)(b * D_ + d)) * L_ + l] = o4;
        }
    }
}

extern "C" void kernel_launch(void* const* d_in, const int* in_sizes, int n_in,
                              void* d_out, int out_size, void* d_ws, size_t ws_size,
                              hipStream_t stream) {
    // Bind inputs by element count (all distinct).
    const float* query = nullptr;  // 4*1024*2048 = 8388608
    const int*   mask  = nullptr;  // 4*2048     = 8192
    const float* W1    = nullptr;  // 2048*1024  = 2097152
    const float* Wq    = nullptr;  // 1024*1024  = 1048576
    for (int i = 0; i < n_in; i++) {
        switch (in_sizes[i]) {
            case 8388608: query = (const float*)d_in[i]; break;
            case 8192:    mask  = (const int*)d_in[i];   break;
            case 2097152: W1    = (const float*)d_in[i]; break;
            case 1048576: Wq    = (const float*)d_in[i]; break;
        }
    }
    float* out = (float*)d_out;  // [4,1024,2048] fp32 (reference output dtype)

    if (ws_size < 50331648u || !query || !mask || !W1 || !Wq) {
        hipLaunchKernelGGL(k_zero_out, dim3((out_size + 255) / 256), dim3(256), 0, stream,
                           out, out_size);
        return;
    }

    // d_out (32 MB fp32) is dead until k_attn -> use its head as projection scratch.
    ushort* Wb = (ushort*)d_out;                       // [3072][1024]      6291456 B
    ushort* Xt = (ushort*)((char*)d_out + 6291456);    // [4][2048][1024]  16777216 B
    char* ws = (char*)d_ws;                            // Qb|Kb|Vt = 48 MB <= gate
    ushort* Qb = (ushort*)(ws + 0);
    ushort* Kb = (ushort*)(ws + 16777216);
    ushort* Vt = (ushort*)(ws + 33554432);

    hipLaunchKernelGGL(k_convert_w, dim3(3072), dim3(256), 0, stream, W1, Wq, Wb);
    hipLaunchKernelGGL(k_transpose, dim3(64, 32, 4), dim3(32, 8), 0, stream, query, Xt);
    hipLaunchKernelGGL(k_proj, dim3(16, 24, 4), dim3(256), 0, stream, Wb, Xt, Qb, Kb, Vt);
    hipLaunchKernelGGL(k_attn, dim3(512), dim3(256), 0, stream, Qb, Kb, Vt, mask, out);
}

// Round 10
// 290.010 us; speedup vs baseline: 1.9876x; 1.3035x over previous
//
#include <hip/hip_runtime.h>
#include <hip/hip_bf16.h>

#define B_  4
#define D_  1024
#define L_  2048
#define H_  8
#define HD_ 128

typedef __attribute__((ext_vector_type(8))) short bf16x8;
typedef __attribute__((ext_vector_type(4))) float f32x4;

static __device__ __forceinline__ ushort f2bf(float f) {
    // round-to-nearest-even fp32 -> bf16 (finite inputs only)
    unsigned u = __float_as_uint(f);
    unsigned r = (u + 0x7fffu + ((u >> 16) & 1u)) >> 16;
    return (ushort)r;
}

// async 16B global->LDS DMA (dest = wave-uniform LDS base + lane*16)
static __device__ __forceinline__ void dma16(const ushort* g, ushort* l) {
    __builtin_amdgcn_global_load_lds(
        (const __attribute__((address_space(1))) void*)g,
        (__attribute__((address_space(3))) void*)l, 16, 0, 0);
}

// ---------------- signal kernel: zero output (signature absmax = 4.589844e-01) ----
__global__ void k_zero_out(float* __restrict__ out, int n) {
    int i = blockIdx.x * 256 + threadIdx.x;
    if (i < n) out[i] = 0.f;
}

// ---------------- Kernel A1: W1||Wq -> bf16 Wb [3072][1024] ----------------
__global__ void k_convert_w(const float* __restrict__ W1, const float* __restrict__ Wq,
                            ushort* __restrict__ Wb) {
    int i = blockIdx.x * 256 + threadIdx.x;     // float4 index, exact grid
    const int n1 = 2 * D_ * D_ / 4;             // 524288 float4s in W1
    float4 v = (i < n1) ? ((const float4*)W1)[i] : ((const float4*)Wq)[i - n1];
    ushort4 o;
    o.x = f2bf(v.x); o.y = f2bf(v.y); o.z = f2bf(v.z); o.w = f2bf(v.w);
    ((ushort4*)Wb)[i] = o;
}

// ---------------- Kernel A2: query[b][d][l] fp32 -> Xt[b][l][d] bf16 ----------------
__global__ void k_transpose(const float* __restrict__ q, ushort* __restrict__ Xt) {
    __shared__ float tile[32][33];
    int b = blockIdx.z, d0 = blockIdx.y * 32, l0 = blockIdx.x * 32;
    int tx = threadIdx.x, ty = threadIdx.y;
    const float* src = q + (size_t)b * D_ * L_;
    for (int i = 0; i < 4; i++)
        tile[ty + 8 * i][tx] = src[(size_t)(d0 + ty + 8 * i) * L_ + l0 + tx];
    __syncthreads();
    ushort* dst = Xt + (size_t)b * L_ * D_;
    for (int i = 0; i < 4; i++)
        dst[(size_t)(l0 + ty + 8 * i) * D_ + d0 + tx] = f2bf(tile[tx][ty + 8 * i]);
}

// ---------------- Kernel B: projection GEMM (MFMA) — unchanged (validated) ------
__launch_bounds__(256)
__global__ void k_proj(const ushort* __restrict__ Wb, const ushort* __restrict__ Xt,
                       ushort* __restrict__ Qb, ushort* __restrict__ Kb,
                       ushort* __restrict__ Vt) {
    __shared__ alignas(16) ushort As[128][72];   // [o][k], +8 pad
    __shared__ alignas(16) ushort Bs[128][72];   // [l][k]
    const int b  = blockIdx.z;
    const int o0 = blockIdx.y * 128;
    const int l0 = blockIdx.x * 128;
    const int t = threadIdx.x;
    const int wave = t >> 6, lane = t & 63, quad = lane >> 4, li = lane & 15;
    const int wm = wave >> 1, wn = wave & 1;
    const ushort* Xb = Xt + (size_t)b * L_ * D_;
    f32x4 acc[4][4] = {};
    const int row = t >> 3;     // 0..31
    const int chunk = t & 7;    // 0..7 (8 bf16 each)

    for (int k0 = 0; k0 < D_; k0 += 64) {
        for (int i = 0; i < 4; i++) {
            int r = row + 32 * i;
            *(float4*)&As[r][chunk * 8] = *(const float4*)&Wb[(size_t)(o0 + r) * D_ + k0 + chunk * 8];
            *(float4*)&Bs[r][chunk * 8] = *(const float4*)&Xb[(size_t)(l0 + r) * D_ + k0 + chunk * 8];
        }
        __syncthreads();
        for (int ks = 0; ks < 64; ks += 32) {
            bf16x8 af[4], bfr[4];
            for (int mf = 0; mf < 4; mf++) af[mf]  = *(const bf16x8*)&As[wm * 64 + mf * 16 + li][ks + quad * 8];
            for (int nf = 0; nf < 4; nf++) bfr[nf] = *(const bf16x8*)&Bs[wn * 64 + nf * 16 + li][ks + quad * 8];
            for (int mf = 0; mf < 4; mf++)
                for (int nf = 0; nf < 4; nf++)
                    acc[mf][nf] = __builtin_amdgcn_mfma_f32_16x16x32_bf16(af[mf], bfr[nf], acc[mf][nf], 0, 0, 0);
        }
        __syncthreads();
    }

    const int type = o0 >> 10;              // 0=K 1=V 2=Q (tile never crosses)
    const float qscale = 0.08838834764831845f;  // HD^-0.5
    for (int mf = 0; mf < 4; mf++) {
        int o = o0 + wm * 64 + mf * 16 + quad * 4;  // v[r] is channel o+r
        int c = o & 1023;
        int h = c >> 7, hd = c & 127;
        for (int nf = 0; nf < 4; nf++) {
            int l = l0 + wn * 64 + nf * 16 + li;
            f32x4 v = acc[mf][nf];
            if (type == 0) {
                ushort4 s4 = { f2bf(v[0]), f2bf(v[1]), f2bf(v[2]), f2bf(v[3]) };
                *(ushort4*)&Kb[(((size_t)(b * H_ + h)) * L_ + l) * HD_ + hd] = s4;
            } else if (type == 1) {
                size_t base = (size_t)(b * H_ + h) * HD_;
                Vt[(base + hd + 0) * L_ + l] = f2bf(v[0]);
                Vt[(base + hd + 1) * L_ + l] = f2bf(v[1]);
                Vt[(base + hd + 2) * L_ + l] = f2bf(v[2]);
                Vt[(base + hd + 3) * L_ + l] = f2bf(v[3]);
            } else {
                ushort4 s4 = { f2bf(v[0] * qscale), f2bf(v[1] * qscale),
                               f2bf(v[2] * qscale), f2bf(v[3] * qscale) };
                *(ushort4*)&Qb[(((size_t)(b * H_ + h)) * L_ + l) * HD_ + hd] = s4;
            }
        }
    }
}

// ---------------- Kernel C: flash attention (MFMA, 4-blocks/CU, async DMA) ------
// block = (b, h, 64 q); 4 waves x 16 q; key blocks of 32; one barrier/iter.
// LDS 37 KB + launch_bounds(256,4) -> 4 blocks/CU for latency hiding.
__launch_bounds__(256, 4)
__global__ void k_attn(const ushort* __restrict__ Qb, const ushort* __restrict__ Kb,
                       const ushort* __restrict__ Vt, const int* __restrict__ mask,
                       float* __restrict__ out) {
    __shared__ alignas(16) ushort Ks[2][32][128];   // 16 KB [buf][key][hd-chunk swizzled]
    __shared__ alignas(16) ushort Vs[2][128][32];   // 16 KB [buf][hd][key-chunk swizzled]
    __shared__ alignas(16) ushort Pl[4][16][40];    //  5 KB per-wave P scratch [q][key+pad]
    const int blk = blockIdx.x;
    const int h = blk & 7, qt = (blk >> 3) & 31, b = blk >> 8;
    const int t = threadIdx.x;
    const int w = t >> 6, lane = t & 63, quad = lane >> 4, li = lane & 15;
    const int q0 = qt * 64 + w * 16;
    const ushort* Qh = Qb + (size_t)(b * H_ + h) * L_ * HD_;
    const ushort* Kh = Kb + (size_t)(b * H_ + h) * L_ * HD_;
    const ushort* Vh = Vt + (size_t)(b * H_ + h) * HD_ * L_;
    const int* mb = mask + b * L_;

    // DMA source pointers (lane-dependent; per-tile offset added at issue).
    // K slot (key,p) holds global hd-chunk p ^ (key&15); lane -> key=seg*4+(l>>4), p=l&15.
    // V slot (hd,p)  holds global key-chunk p ^ (hd&3);  lane -> hd=seg*16+(l>>2), p=l&3.
    const ushort* kgp[2]; const ushort* vgp[2];
    for (int i = 0; i < 2; i++) {
        int seg = w * 2 + i;                       // 0..7
        int key = seg * 4 + (lane >> 4);           // 0..31
        int ck  = (lane & 15) ^ (key & 15);
        kgp[i] = Kh + (size_t)key * HD_ + ck * 8;
        int hd  = seg * 16 + (lane >> 2);          // 0..127
        int cv  = (lane & 3) ^ (hd & 3);
        vgp[i] = Vh + (size_t)hd * L_ + cv * 8;
    }

    // prologue: DMA tile 0 into buf 0
    for (int i = 0; i < 2; i++) dma16(kgp[i], &Ks[0][0][0] + (w * 2 + i) * 512);
    for (int i = 0; i < 2; i++) dma16(vgp[i], &Vs[0][0][0] + (w * 2 + i) * 512);

    // Q as B-fragments (global, linear): qf[kf], n = q = li
    bf16x8 qf[4];
    for (int kf = 0; kf < 4; kf++)
        qf[kf] = *(const bf16x8*)&Qh[(size_t)(q0 + li) * HD_ + kf * 32 + quad * 8];

    float mrun = -1e30f, lrun = 0.f;
    f32x4 acc[8] = {};   // PV C-layout: row q = quad*4+r, col hd = li + 16*nf2

    int buf = 0;
    for (int n0 = 0; n0 < L_; n0 += 32, buf ^= 1) {
        __syncthreads();   // buf's DMA drained+visible; all waves past prior buf reads

        if (n0 + 32 < L_) {  // uniform: issue next tile's DMA into other buffer
            int nb = buf ^ 1;
            for (int i = 0; i < 2; i++)
                dma16(kgp[i] + (size_t)(n0 + 32) * HD_, &Ks[nb][0][0] + (w * 2 + i) * 512);
            for (int i = 0; i < 2; i++)
                dma16(vgp[i] + (n0 + 32), &Vs[nb][0][0] + (w * 2 + i) * 512);
        }

        // mask -> additive bias (L2-hot int4 loads)
        f32x4 bv[2];
        for (int mt = 0; mt < 2; mt++) {
            int4 mk = *(const int4*)&mb[n0 + mt * 16 + quad * 4];
            bv[mt][0] = mk.x ? 0.f : -1e30f;
            bv[mt][1] = mk.y ? 0.f : -1e30f;
            bv[mt][2] = mk.z ? 0.f : -1e30f;
            bv[mt][3] = mk.w ? 0.f : -1e30f;
        }

        // S^T = K(A) x Q^T(B): s[mt][r]: key = mt*16+quad*4+r, q = li
        f32x4 s[2] = {};
        for (int kf = 0; kf < 4; kf++) {
            bf16x8 kfr[2];
            for (int mt = 0; mt < 2; mt++)
                kfr[mt] = *(const bf16x8*)&Ks[buf][mt * 16 + li][((kf * 4 + quad) ^ li) * 8];
            for (int mt = 0; mt < 2; mt++)
                s[mt] = __builtin_amdgcn_mfma_f32_16x16x32_bf16(kfr[mt], qf[kf], s[mt], 0, 0, 0);
        }
        for (int mt = 0; mt < 2; mt++)
            for (int r = 0; r < 4; r++)
                s[mt][r] += bv[mt][r];

        // softmax over this 32-key tile (q = li)
        float a0 = fmaxf(fmaxf(s[0][0], s[0][1]), fmaxf(s[0][2], s[0][3]));
        float a1 = fmaxf(fmaxf(s[1][0], s[1][1]), fmaxf(s[1][2], s[1][3]));
        float nm = fmaxf(a0, a1);
        nm = fmaxf(nm, __shfl_xor(nm, 16, 64));
        nm = fmaxf(nm, __shfl_xor(nm, 32, 64));
        float mnew = fmaxf(mrun, nm);
        float alpha = __expf(mrun - mnew);
        mrun = mnew;
        float rs = 0.f;
        for (int mt = 0; mt < 2; mt++)
            for (int r = 0; r < 4; r++) {
                float p = __expf(s[mt][r] - mnew);
                s[mt][r] = p;
                rs += p;
            }
        rs += __shfl_xor(rs, 16, 64);
        rs += __shfl_xor(rs, 32, 64);
        lrun = lrun * alpha + rs;

        // rescale acc only when the running max actually moved (common case: skip)
        if (__any(alpha != 1.0f)) {
            int sb = (lane & 48) | (quad * 4);     // lane with li = quad*4 (+r)
            float ar0 = __shfl(alpha, sb + 0, 64);
            float ar1 = __shfl(alpha, sb + 1, 64);
            float ar2 = __shfl(alpha, sb + 2, 64);
            float ar3 = __shfl(alpha, sb + 3, 64);
            for (int nf2 = 0; nf2 < 8; nf2++) {
                acc[nf2][0] *= ar0;
                acc[nf2][1] *= ar1;
                acc[nf2][2] *= ar2;
                acc[nf2][3] *= ar3;
            }
        }

        // P write: Pl[w][q=li][key = mt*16+quad*4+r]
        for (int mt = 0; mt < 2; mt++) {
            ushort4 pk = { f2bf(s[mt][0]), f2bf(s[mt][1]),
                           f2bf(s[mt][2]), f2bf(s[mt][3]) };
            *(ushort4*)&Pl[w][li][mt * 16 + quad * 4] = pk;
        }

        // PV: A = P (per-wave LDS, m=q=li, k=key), B = V from staged LDS
        bf16x8 pa = *(const bf16x8*)&Pl[w][li][quad * 8];
        for (int nf2 = 0; nf2 < 8; nf2++) {
            bf16x8 vb = *(const bf16x8*)&Vs[buf][nf2 * 16 + li][(quad ^ (li & 3)) * 8];
            acc[nf2] = __builtin_amdgcn_mfma_f32_16x16x32_bf16(pa, vb, acc[nf2], 0, 0, 0);
        }
    }

    // epilogue: redistribute 1/l to row-space, float4 stores (4 consecutive l)
    float inv = 1.0f / lrun;
    int sb = (lane & 48) | (quad * 4);
    float i0 = __shfl(inv, sb + 0, 64);
    float i1 = __shfl(inv, sb + 1, 64);
    float i2 = __shfl(inv, sb + 2, 64);
    float i3 = __shfl(inv, sb + 3, 64);
    int l = q0 + quad * 4;
    for (int nf2 = 0; nf2 < 8; nf2++) {
        int d = h * HD_ + nf2 * 16 + li;
        float4 o4 = { acc[nf2][0] * i0, acc[nf2][1] * i1,
                      acc[nf2][2] * i2, acc[nf2][3] * i3 };
        *(float4*)&out[((size_t)(b * D_ + d)) * L_ + l] = o4;
    }
}

extern "C" void kernel_launch(void* const* d_in, const int* in_sizes, int n_in,
                              void* d_out, int out_size, void* d_ws, size_t ws_size,
                              hipStream_t stream) {
    // Bind inputs by element count (all distinct).
    const float* query = nullptr;  // 4*1024*2048 = 8388608
    const int*   mask  = nullptr;  // 4*2048     = 8192
    const float* W1    = nullptr;  // 2048*1024  = 2097152
    const float* Wq    = nullptr;  // 1024*1024  = 1048576
    for (int i = 0; i < n_in; i++) {
        switch (in_sizes[i]) {
            case 8388608: query = (const float*)d_in[i]; break;
            case 8192:    mask  = (const int*)d_in[i];   break;
            case 2097152: W1    = (const float*)d_in[i]; break;
            case 1048576: Wq    = (const float*)d_in[i]; break;
        }
    }
    float* out = (float*)d_out;  // [4,1024,2048] fp32 (reference output dtype)

    if (ws_size < 50331648u || !query || !mask || !W1 || !Wq) {
        hipLaunchKernelGGL(k_zero_out, dim3((out_size + 255) / 256), dim3(256), 0, stream,
                           out, out_size);
        return;
    }

    // d_out (32 MB fp32) is dead until k_attn -> use its head as projection scratch.
    ushort* Wb = (ushort*)d_out;                       // [3072][1024]      6291456 B
    ushort* Xt = (ushort*)((char*)d_out + 6291456);    // [4][2048][1024]  16777216 B
    char* ws = (char*)d_ws;                            // Qb|Kb|Vt = 48 MB <= gate
    ushort* Qb = (ushort*)(ws + 0);
    ushort* Kb = (ushort*)(ws + 16777216);
    ushort* Vt = (ushort*)(ws + 33554432);

    hipLaunchKernelGGL(k_convert_w, dim3(3072), dim3(256), 0, stream, W1, Wq, Wb);
    hipLaunchKernelGGL(k_transpose, dim3(64, 32, 4), dim3(32, 8), 0, stream, query, Xt);
    hipLaunchKernelGGL(k_proj, dim3(16, 24, 4), dim3(256), 0, stream, Wb, Xt, Qb, Kb, Vt);
    hipLaunchKernelGGL(k_attn, dim3(1024), dim3(256), 0, stream, Qb, Kb, Vt, mask, out);
}